// Round 10
// baseline (106.418 us; speedup 1.0000x reference)
//
#include <hip/hip_runtime.h>

static constexpr int B_ROWS  = 262144;
static constexpr int D       = 256;
static constexpr int NSAMP   = 5;
static constexpr int BLOCK   = 256;           // 4 waves
static constexpr int NBLOCKS = 2048;          // 8192 waves x 32 rows/wave
static constexpr int WPB     = BLOCK / 64;
static constexpr int RPS     = 4;             // rows per pipeline step
static constexpr int NSTEP   = 8;             // 32 rows/wave

// log(max(sigmoid(x), eps))   = -min(log(1+e^{-x}), -ln eps)
// log(max(sigmoid(-x), 0.75)) = -min(log(1+e^{x}),  -ln 0.75)
static constexpr float NEG_LN_EPS  = 20.723265836946411f;   // -ln(1e-9)
static constexpr float NEG_LN_BETA = 0.28768207245178085f;  // -ln(0.75)

typedef __attribute__((address_space(3))) void       lds_void;
typedef const __attribute__((address_space(1))) void g_void;

__device__ __forceinline__ float dot4(const float4 a, const float4 b) {
    return a.x * b.x + a.y * b.y + a.z * b.z + a.w * b.w;
}

// Stage 4 FULL rows of ctx and tgt into LDS: 8 x global_load_lds, each moving
// one entire contiguous 1 KB row (64 lanes x 16 B). The DRAM-visible stream per
// wave is sequential 1 KB bursts (fillBuffer-like), unlike the 64 B x 1KB-stride
// scatter of all previous rounds. LDS dest is wave-uniform base + lane*16
// (rule #21) -> row-major [RPS][256] exactly.
__device__ __forceinline__ void issue_step(
    const float* __restrict__ ctx, const float* __restrict__ tgt,
    float* dst_c, float* dst_t, int rowbase, int lane)
{
#pragma unroll
    for (int k = 0; k < RPS; ++k) {
        const float* gc = ctx + (size_t)(rowbase + k) * D + lane * 4;
        const float* gt = tgt + (size_t)(rowbase + k) * D + lane * 4;
        __builtin_amdgcn_global_load_lds((g_void*)gc, (lds_void*)(dst_c + k * D), 16, 0, 0);
        __builtin_amdgcn_global_load_lds((g_void*)gt, (lds_void*)(dst_t + k * D), 16, 0, 0);
    }
}

__global__ __launch_bounds__(BLOCK) void sgns_main(
    const float* __restrict__ ctx, const float* __restrict__ tgt,
    const float* __restrict__ emb, const int* __restrict__ neg_idx,
    float* __restrict__ partials)
{
    __shared__ float smp[NSAMP][D];               // 5 KB; 2-way-max reads (free)
    __shared__ float stage[WPB][2][2][RPS][D];    // 4 waves x 16 KB = 64 KB
    for (int i = threadIdx.x; i < NSAMP * D; i += BLOCK) {
        const int s = i >> 8, c = i & (D - 1);
        smp[s][c] = emb[(size_t)neg_idx[s] * D + c];
    }
    __syncthreads();

    const int lane = threadIdx.x & 63;
    const int wid  = threadIdx.x >> 6;
    const int g4   = lane >> 4;       // 0..3: which row of the step
    const int s16  = lane & 15;       // granule index within the row
    const int gwave = blockIdx.x * WPB + wid;
    const int R = gwave * (RPS * NSTEP);          // this wave's 32 contiguous rows

    float acc = 0.0f;

    // Prologue: stage step 0 into buf 0.
    issue_step(ctx, tgt, &stage[wid][0][0][0][0], &stage[wid][0][1][0][0], R, lane);

#pragma unroll
    for (int s = 0; s < NSTEP; ++s) {
        const int b = s & 1;
        if (s + 1 < NSTEP) {
            issue_step(ctx, tgt, &stage[wid][b ^ 1][0][0][0],
                       &stage[wid][b ^ 1][1][0][0], R + (s + 1) * RPS, lane);
            asm volatile("s_waitcnt vmcnt(8)" ::: "memory");  // buf b's 8 loads done
        } else {
            asm volatile("s_waitcnt vmcnt(0)" ::: "memory");
        }
        __builtin_amdgcn_sched_barrier(0);  // rule #18: no ds_read hoists above the wait

        // Row R+s*4+g4, full 256 cols over 4 m-iters. Bank pattern: word index
        // = g4*256 + (m*16+s16)*4 -> bank 4*(s16 mod 8): exactly 8 lanes per
        // bank-quad (uniform b128 floor, conflict-free).
        float d0 = 0.f, d1 = 0.f, d2 = 0.f, d3 = 0.f, d4 = 0.f, d5 = 0.f;
#pragma unroll
        for (int m = 0; m < 4; ++m) {
            const int gw = (m * 16 + s16) * 4;
            const float4 c4 = *reinterpret_cast<const float4*>(&stage[wid][b][0][g4][gw]);
            const float4 t4 = *reinterpret_cast<const float4*>(&stage[wid][b][1][g4][gw]);
            const float4 s0 = *reinterpret_cast<const float4*>(&smp[0][gw]);
            const float4 s1 = *reinterpret_cast<const float4*>(&smp[1][gw]);
            const float4 s2 = *reinterpret_cast<const float4*>(&smp[2][gw]);
            const float4 s3 = *reinterpret_cast<const float4*>(&smp[3][gw]);
            const float4 s4 = *reinterpret_cast<const float4*>(&smp[4][gw]);
            d0 += dot4(c4, t4);
            d1 += dot4(c4, s0);
            d2 += dot4(c4, s1);
            d3 += dot4(c4, s2);
            d4 += dot4(c4, s3);
            d5 += dot4(c4, s4);
        }

        // Reduce across the 16-lane group (offsets 1,2,4,8).
#pragma unroll
        for (int off = 1; off < 16; off <<= 1) {
            d0 += __shfl_xor(d0, off, 64);
            d1 += __shfl_xor(d1, off, 64);
            d2 += __shfl_xor(d2, off, 64);
            d3 += __shfl_xor(d3, off, 64);
            d4 += __shfl_xor(d4, off, 64);
            d5 += __shfl_xor(d5, off, 64);
        }

        float row_loss = -fminf(__logf(1.0f + __expf(-d0)), NEG_LN_EPS);
        row_loss -= fminf(__logf(1.0f + __expf(d1)), NEG_LN_BETA);
        row_loss -= fminf(__logf(1.0f + __expf(d2)), NEG_LN_BETA);
        row_loss -= fminf(__logf(1.0f + __expf(d3)), NEG_LN_BETA);
        row_loss -= fminf(__logf(1.0f + __expf(d4)), NEG_LN_BETA);
        row_loss -= fminf(__logf(1.0f + __expf(d5)), NEG_LN_BETA);
        acc += row_loss;   // identical across the 16 lanes of this group
    }

    // Cross-group reduce: lanes {l, l^16, l^32, l^48} hold the 4 DISTINCT group
    // accs (within-group lanes are never summed together), so this butterfly
    // counts each group's value exactly once -> NO division needed.
    // (r9 bug: an erroneous *=1/16 here divided the correct total by 16.)
    acc += __shfl_xor(acc, 16, 64);
    acc += __shfl_xor(acc, 32, 64);

    __shared__ float blk[WPB];
    if (lane == 0) blk[wid] = acc;
    __syncthreads();
    if (threadIdx.x == 0) {
        float s = 0.0f;
#pragma unroll
        for (int i = 0; i < WPB; ++i) s += blk[i];
        partials[blockIdx.x] = s;
    }
}

__global__ __launch_bounds__(256) void sgns_reduce(
    const float* __restrict__ partials, float* __restrict__ out)
{
    float s = 0.0f;
    for (int i = threadIdx.x; i < NBLOCKS; i += 256) s += partials[i];
#pragma unroll
    for (int off = 32; off > 0; off >>= 1) s += __shfl_xor(s, off, 64);
    __shared__ float lds[4];
    if ((threadIdx.x & 63) == 0) lds[threadIdx.x >> 6] = s;
    __syncthreads();
    if (threadIdx.x == 0) out[0] = lds[0] + lds[1] + lds[2] + lds[3];
}

extern "C" void kernel_launch(void* const* d_in, const int* in_sizes, int n_in,
                              void* d_out, int out_size, void* d_ws, size_t ws_size,
                              hipStream_t stream) {
    const float* ctx     = (const float*)d_in[0];
    const float* tgt     = (const float*)d_in[1];
    const float* emb     = (const float*)d_in[2];
    const int*   neg_idx = (const int*)d_in[3];
    float* out      = (float*)d_out;
    float* partials = (float*)d_ws;  // NBLOCKS floats = 8 KB

    sgns_main<<<NBLOCKS, BLOCK, 0, stream>>>(ctx, tgt, emb, neg_idx, partials);
    sgns_reduce<<<1, 256, 0, stream>>>(partials, out);
}